// Round 1
// baseline (267.444 us; speedup 1.0000x reference)
//
#include <hip/hip_runtime.h>

typedef unsigned short u16;
typedef __bf16 bf16x8 __attribute__((ext_vector_type(8)));
typedef float f32x4 __attribute__((ext_vector_type(4)));

// ---- problem constants ----
constexpr int SEQ = 2048;
constexpr int HIDN = 2880;
constexpr int NHEAD = 64;
constexpr int NKVH = 8;
constexpr int DHEAD = 64;
constexpr int NQKV = 5120;   // 4096 q | 512 k | 512 v
constexpr float SCALE = 0.125f;   // 1/sqrt(64)
constexpr float NEG_INF = -1e30f;

__device__ __forceinline__ u16 f2bf(float f) {
  unsigned int u = __builtin_bit_cast(unsigned int, f);
  u += 0x7FFFu + ((u >> 16) & 1u);
  return (u16)(u >> 16);
}
__device__ __forceinline__ float bf2f(u16 h) {
  unsigned int u = ((unsigned int)h) << 16;
  return __builtin_bit_cast(float, u);
}
__device__ __forceinline__ void async_load16(const void* g, void* l) {
  __builtin_amdgcn_global_load_lds(
      (const __attribute__((address_space(1))) unsigned int*)g,
      (__attribute__((address_space(3))) unsigned int*)l, 16, 0, 0);
}

// ---- fp32 -> bf16 flat convert ----
__global__ __launch_bounds__(256) void conv_f2b(const float* __restrict__ in,
                                                u16* __restrict__ out, long n4) {
  long i = (long)blockIdx.x * 256 + threadIdx.x;
  if (i >= n4) return;
  float4 v = ((const float4*)in)[i];
  u16 o0 = f2bf(v.x), o1 = f2bf(v.y), o2 = f2bf(v.z), o3 = f2bf(v.w);
  out[i * 4 + 0] = o0; out[i * 4 + 1] = o1; out[i * 4 + 2] = o2; out[i * 4 + 3] = o3;
}

// ---- fp32 [R][C] -> bf16 out[c][r] (transpose-convert), dims % 32 == 0 ----
__global__ __launch_bounds__(256) void transpose_f2b(const float* __restrict__ in,
                                                     u16* __restrict__ out,
                                                     int R, int C, int ostride) {
  __shared__ float tile[32][33];
  int c0 = blockIdx.x * 32, r0 = blockIdx.y * 32;
  int tx = threadIdx.x & 31, ty = threadIdx.x >> 5;  // ty in 0..7
#pragma unroll
  for (int i = 0; i < 32; i += 8)
    tile[ty + i][tx] = in[(long)(r0 + ty + i) * C + c0 + tx];
  __syncthreads();
#pragma unroll
  for (int i = 0; i < 32; i += 8)
    out[(long)(c0 + ty + i) * ostride + r0 + tx] = f2bf(tile[tx][ty + i]);
}

// ---- concat biases bq|bk|bv -> [5120] fp32 ----
__global__ __launch_bounds__(256) void concat_bias(const float* bq, const float* bk,
                                                   const float* bv, float* out) {
  int t = blockIdx.x * 256 + threadIdx.x;
  if (t < 4096) out[t] = bq[t];
  else if (t < 4608) out[t] = bk[t - 4096];
  else if (t < 5120) out[t] = bv[t - 4608];
}

// ---- GEMM: C[M][N] = A[M][K] @ B_t[N][K]^T + bias; 128x128 tile, BK=32 ----
template <bool OUT_BF16>
__global__ __launch_bounds__(256, 2) void gemm_bt(const u16* __restrict__ A,
                                                  const u16* __restrict__ B,
                                                  const float* __restrict__ bias,
                                                  void* __restrict__ Cout,
                                                  int M, int N, int K) {
  __shared__ u16 As[128 * 32];
  __shared__ u16 Bs[128 * 32];
  const int tid = threadIdx.x;
  const int wid = tid >> 6, lane = tid & 63;
  const int lr = lane & 15, lk = lane >> 4;
  const int wm = wid >> 1, wn = wid & 1;
  const long brow = (long)blockIdx.x * 128;
  const long bcol = (long)blockIdx.y * 128;

  f32x4 acc[4][4] = {};
  const int nk = K >> 5;
  for (int kt = 0; kt < nk; ++kt) {
    const long k0 = (long)kt * 32;
#pragma unroll
    for (int i = 0; i < 2; ++i) {
      int c = wid * 128 + i * 64 + lane;        // 0..511
      int row = c >> 2, sub = c & 3;
      async_load16(A + (brow + row) * K + k0 + sub * 8, ((char*)As) + c * 16);
      async_load16(B + (bcol + row) * K + k0 + sub * 8, ((char*)Bs) + c * 16);
    }
    __syncthreads();
    bf16x8 af[4], bfr[4];
#pragma unroll
    for (int m = 0; m < 4; ++m)
      af[m] = *(const bf16x8*)&As[(wm * 64 + m * 16 + lr) * 32 + lk * 8];
#pragma unroll
    for (int n = 0; n < 4; ++n)
      bfr[n] = *(const bf16x8*)&Bs[(wn * 64 + n * 16 + lr) * 32 + lk * 8];
#pragma unroll
    for (int m = 0; m < 4; ++m)
#pragma unroll
      for (int n = 0; n < 4; ++n)
        acc[m][n] = __builtin_amdgcn_mfma_f32_16x16x32_bf16(af[m], bfr[n], acc[m][n], 0, 0, 0);
    __syncthreads();
  }
  // epilogue
#pragma unroll
  for (int m = 0; m < 4; ++m) {
    long row = brow + wm * 64 + m * 16 + lk * 4;
#pragma unroll
    for (int n = 0; n < 4; ++n) {
      long col = bcol + wn * 64 + n * 16 + lr;
      if (col < N) {
        float bv = bias[col];
#pragma unroll
        for (int r = 0; r < 4; ++r) {
          float v = acc[m][n][r] + bv;
          if (OUT_BF16) ((u16*)Cout)[(row + r) * (long)N + col] = f2bf(v);
          else          ((float*)Cout)[(row + r) * (long)N + col] = v;
        }
      }
    }
  }
}

// ---- RoPE in-place on QKV bf16 buffer (q heads 0..63, k heads 64..71) ----
__global__ __launch_bounds__(256) void rope_kernel(u16* __restrict__ QKV,
                                                   const float* __restrict__ cosb,
                                                   const float* __restrict__ sinb) {
  long idx = (long)blockIdx.x * 256 + threadIdx.x;  // SEQ*72*32
  if (idx >= (long)SEQ * 72 * 32) return;
  int d = idx & 31;
  int h = (int)((idx >> 5) % 72);
  int s = (int)(idx / (72 * 32));
  int col = (h < 64) ? h * 64 : 4096 + (h - 64) * 64;
  u16* p = QKV + (long)s * NQKV + col;
  float x1 = bf2f(p[d]), x2 = bf2f(p[d + 32]);
  float c = cosb[s * 64 + d], sn = sinb[s * 64 + d];
  p[d]      = f2bf(x1 * c - x2 * sn);
  p[d + 32] = f2bf(x2 * c + x1 * sn);
}

// ---- sliding-window attention with sinks ----
// grid: (SEQ/64, NHEAD/4); block 256 (4 waves, 1 head each, shared KV group)
__global__ __launch_bounds__(256, 1) void attn_kernel(const u16* __restrict__ QKV,
                                                      const float* __restrict__ sinks,
                                                      u16* __restrict__ Oa) {
  __shared__ u16 Ks[64 * 64];
  __shared__ u16 Vt[64 * 64];        // [d][j]
  __shared__ u16 Ps[4][64 * 72];     // per-wave P, padded stride 72
  const int tid = threadIdx.x, wid = tid >> 6, lane = tid & 63;
  const int lr = lane & 15, lk = lane >> 4;
  const int i0 = blockIdx.x * 64;
  const int h = blockIdx.y * 4 + wid;
  const int g = h >> 3;

  // Q fragments (post-RoPE, bf16)
  bf16x8 qf[4][2];
#pragma unroll
  for (int m = 0; m < 4; ++m)
#pragma unroll
    for (int kc = 0; kc < 2; ++kc)
      qf[m][kc] = *(const bf16x8*)&QKV[(long)(i0 + m * 16 + lr) * NQKV + h * 64 + kc * 32 + lk * 8];

  const float sinkh = sinks[h];
  float mrun[4][4], lrun[4][4];
  f32x4 oacc[4][4] = {};
#pragma unroll
  for (int m = 0; m < 4; ++m)
#pragma unroll
    for (int r = 0; r < 4; ++r) { mrun[m][r] = sinkh; lrun[m][r] = 0.f; }

  const int jb0 = (i0 >= 128) ? (i0 - 128) : 0;
  for (int jb = jb0; jb <= i0; jb += 64) {
    // K block -> LDS (async, linear)
#pragma unroll
    for (int i = 0; i < 2; ++i) {
      int c = wid * 128 + i * 64 + lane;  // 0..511
      int row = c >> 3, sub = c & 7;
      async_load16(QKV + (long)(jb + row) * NQKV + 4096 + g * 64 + sub * 8,
                   ((char*)Ks) + c * 16);
    }
    // V block -> LDS transposed [d][j]
    {
      int j = tid >> 2, d0 = (tid & 3) * 16;
      const u16* vp = QKV + (long)(jb + j) * NQKV + 4608 + g * 64 + d0;
      u16 tmp[16];
      *(int4*)(tmp)     = *(const int4*)(vp);
      *(int4*)(tmp + 8) = *(const int4*)(vp + 8);
#pragma unroll
      for (int e = 0; e < 16; ++e) Vt[(d0 + e) * 64 + j] = tmp[e];
    }
    __syncthreads();

    // S = Q K^T
    f32x4 sf[4][4] = {};
#pragma unroll
    for (int kc = 0; kc < 2; ++kc) {
      bf16x8 kf[4];
#pragma unroll
      for (int cf = 0; cf < 4; ++cf)
        kf[cf] = *(const bf16x8*)&Ks[(cf * 16 + lr) * 64 + kc * 32 + lk * 8];
#pragma unroll
      for (int m = 0; m < 4; ++m)
#pragma unroll
        for (int cf = 0; cf < 4; ++cf)
          sf[m][cf] = __builtin_amdgcn_mfma_f32_16x16x32_bf16(qf[m][kc], kf[cf], sf[m][cf], 0, 0, 0);
    }

    // scale + mask + online softmax
#pragma unroll
    for (int m = 0; m < 4; ++m) {
      float rmax[4];
#pragma unroll
      for (int r = 0; r < 4; ++r) {
        int i = i0 + m * 16 + lk * 4 + r;
        float mx = NEG_INF;
#pragma unroll
        for (int cf = 0; cf < 4; ++cf) {
          int j = jb + cf * 16 + lr;
          float v = sf[m][cf][r] * SCALE;
          bool ok = (j <= i) && (j > i - 128);
          v = ok ? v : NEG_INF;
          sf[m][cf][r] = v;
          mx = fmaxf(mx, v);
        }
#pragma unroll
        for (int off = 1; off < 16; off <<= 1) mx = fmaxf(mx, __shfl_xor(mx, off, 64));
        rmax[r] = mx;
      }
#pragma unroll
      for (int r = 0; r < 4; ++r) {
        float mnew = fmaxf(mrun[m][r], rmax[r]);
        float corr = __expf(mrun[m][r] - mnew);
        mrun[m][r] = mnew;
        float rsum = 0.f;
#pragma unroll
        for (int cf = 0; cf < 4; ++cf) {
          float p = __expf(sf[m][cf][r] - mnew);
          sf[m][cf][r] = p;
          rsum += p;
        }
#pragma unroll
        for (int off = 1; off < 16; off <<= 1) rsum += __shfl_xor(rsum, off, 64);
        lrun[m][r] = lrun[m][r] * corr + rsum;
#pragma unroll
        for (int dn = 0; dn < 4; ++dn) oacc[m][dn][r] *= corr;
      }
    }

    // P -> bf16 -> LDS (C-layout rows)
#pragma unroll
    for (int m = 0; m < 4; ++m)
#pragma unroll
      for (int cf = 0; cf < 4; ++cf)
#pragma unroll
        for (int r = 0; r < 4; ++r)
          Ps[wid][(m * 16 + lk * 4 + r) * 72 + cf * 16 + lr] = f2bf(sf[m][cf][r]);
    __syncthreads();

    // O += P V
#pragma unroll
    for (int kc = 0; kc < 2; ++kc) {
      bf16x8 pf[4], vf[4];
#pragma unroll
      for (int m = 0; m < 4; ++m)
        pf[m] = *(const bf16x8*)&Ps[wid][(m * 16 + lr) * 72 + kc * 32 + lk * 8];
#pragma unroll
      for (int dn = 0; dn < 4; ++dn)
        vf[dn] = *(const bf16x8*)&Vt[(dn * 16 + lr) * 64 + kc * 32 + lk * 8];
#pragma unroll
      for (int m = 0; m < 4; ++m)
#pragma unroll
        for (int dn = 0; dn < 4; ++dn)
          oacc[m][dn] = __builtin_amdgcn_mfma_f32_16x16x32_bf16(pf[m], vf[dn], oacc[m][dn], 0, 0, 0);
    }
    __syncthreads();
  }

  // epilogue: divide by denom (incl. sink) and store bf16
#pragma unroll
  for (int m = 0; m < 4; ++m)
#pragma unroll
    for (int r = 0; r < 4; ++r) {
      float denom = lrun[m][r] + __expf(sinkh - mrun[m][r]);
      float inv = 1.f / denom;
      long row = i0 + m * 16 + lk * 4 + r;
#pragma unroll
      for (int dn = 0; dn < 4; ++dn)
        Oa[row * 4096 + h * 64 + dn * 16 + lr] = f2bf(oacc[m][dn][r] * inv);
    }
}

extern "C" void kernel_launch(void* const* d_in, const int* in_sizes, int n_in,
                              void* d_out, int out_size, void* d_ws, size_t ws_size,
                              hipStream_t stream) {
  const float* X    = (const float*)d_in[0];
  const float* cosb = (const float*)d_in[1];
  const float* sinb = (const float*)d_in[2];
  const float* Wq   = (const float*)d_in[3];
  const float* bq   = (const float*)d_in[4];
  const float* Wk   = (const float*)d_in[5];
  const float* bk   = (const float*)d_in[6];
  const float* Wv   = (const float*)d_in[7];
  const float* bv   = (const float*)d_in[8];
  const float* Wo   = (const float*)d_in[9];
  const float* bo   = (const float*)d_in[10];
  const float* sinks = (const float*)d_in[11];

  char* ws = (char*)d_ws;
  size_t off = 0;
  auto alloc = [&](size_t bytes) -> void* {
    void* p = ws + off;
    off += (bytes + 255) & ~(size_t)255;
    return p;
  };
  u16*   Xb    = (u16*)alloc((size_t)SEQ * HIDN * 2);            // [2048][2880]
  u16*   Wqkv  = (u16*)alloc((size_t)NQKV * HIDN * 2);           // [5120][2880]
  u16*   Wot   = (u16*)alloc((size_t)2944 * 4096 * 2);           // [2944][4096] (pad rows)
  float* bqkv  = (float*)alloc((size_t)NQKV * 4);
  u16*   QKV   = (u16*)alloc((size_t)SEQ * NQKV * 2);            // [2048][5120]
  u16*   Ab    = (u16*)alloc((size_t)SEQ * 4096 * 2);            // attn out [2048][4096]
  (void)ws_size; (void)in_sizes; (void)n_in; (void)out_size;

  // 1) convert hidden to bf16
  conv_f2b<<<(SEQ * HIDN / 4 + 255) / 256, 256, 0, stream>>>(X, Xb, (long)SEQ * HIDN / 4);
  // 2) transpose-convert weights into B^T bf16 layouts
  transpose_f2b<<<dim3(4096 / 32, HIDN / 32), 256, 0, stream>>>(Wq, Wqkv, HIDN, 4096, HIDN);
  transpose_f2b<<<dim3(512 / 32, HIDN / 32), 256, 0, stream>>>(Wk, Wqkv + (size_t)4096 * HIDN, HIDN, 512, HIDN);
  transpose_f2b<<<dim3(512 / 32, HIDN / 32), 256, 0, stream>>>(Wv, Wqkv + (size_t)4608 * HIDN, HIDN, 512, HIDN);
  transpose_f2b<<<dim3(HIDN / 32, 4096 / 32), 256, 0, stream>>>(Wo, Wot, 4096, HIDN, 4096);
  concat_bias<<<(NQKV + 255) / 256, 256, 0, stream>>>(bq, bk, bv, bqkv);
  // 3) QKV projection (bf16 out)
  gemm_bt<true><<<dim3(SEQ / 128, NQKV / 128), 256, 0, stream>>>(Xb, Wqkv, bqkv, QKV, SEQ, NQKV, HIDN);
  // 4) RoPE on q,k
  rope_kernel<<<(int)(((long)SEQ * 72 * 32 + 255) / 256), 256, 0, stream>>>(QKV, cosb, sinb);
  // 5) sliding-window attention with sinks
  attn_kernel<<<dim3(SEQ / 64, NHEAD / 4), 256, 0, stream>>>(QKV, sinks, Ab);
  // 6) output projection (fp32 out + bo)
  gemm_bt<false><<<dim3(SEQ / 128, (HIDN + 127) / 128), 256, 0, stream>>>(Ab, Wot, bo, d_out, SEQ, HIDN, 4096);
}

// Round 2
// 259.693 us; speedup vs baseline: 1.0298x; 1.0298x over previous
//
#include <hip/hip_runtime.h>

typedef unsigned short u16;
typedef __bf16 bf16x8 __attribute__((ext_vector_type(8)));
typedef float f32x4 __attribute__((ext_vector_type(4)));

// ---- problem constants ----
constexpr int SEQ = 2048;
constexpr int HIDN = 2880;
constexpr int NQKV = 5120;   // 4096 q | 512 k | 512 v
constexpr float SCALE = 0.125f;   // 1/sqrt(64)
constexpr float NEG_INF = -1e30f;

#define ASM_VMCNT4()  asm volatile("s_waitcnt vmcnt(4)" ::: "memory")
#define ASM_VMCNT0()  asm volatile("s_waitcnt vmcnt(0)" ::: "memory")
#define ASM_LGKM0()   asm volatile("s_waitcnt lgkmcnt(0)" ::: "memory")
#define ASM_BARRIER() asm volatile("s_barrier" ::: "memory")

__device__ __forceinline__ u16 f2bf(float f) {
  unsigned int u = __builtin_bit_cast(unsigned int, f);
  u += 0x7FFFu + ((u >> 16) & 1u);
  return (u16)(u >> 16);
}
__device__ __forceinline__ float bf2f(u16 h) {
  unsigned int u = ((unsigned int)h) << 16;
  return __builtin_bit_cast(float, u);
}
__device__ __forceinline__ void async_load16(const void* g, void* l) {
  __builtin_amdgcn_global_load_lds(
      (const __attribute__((address_space(1))) unsigned int*)g,
      (__attribute__((address_space(3))) unsigned int*)l, 16, 0, 0);
}

// ---- fp32 -> bf16 flat convert ----
__global__ __launch_bounds__(256) void conv_f2b(const float* __restrict__ in,
                                                u16* __restrict__ out, long n4) {
  long i = (long)blockIdx.x * 256 + threadIdx.x;
  if (i >= n4) return;
  float4 v = ((const float4*)in)[i];
  u16 o0 = f2bf(v.x), o1 = f2bf(v.y), o2 = f2bf(v.z), o3 = f2bf(v.w);
  out[i * 4 + 0] = o0; out[i * 4 + 1] = o1; out[i * 4 + 2] = o2; out[i * 4 + 3] = o3;
}

// ---- fp32 [R][C] -> bf16 out[c][r] (transpose-convert), dims % 32 == 0 ----
__global__ __launch_bounds__(256) void transpose_f2b(const float* __restrict__ in,
                                                     u16* __restrict__ out,
                                                     int R, int C, int ostride) {
  __shared__ float tile[32][33];
  int c0 = blockIdx.x * 32, r0 = blockIdx.y * 32;
  int tx = threadIdx.x & 31, ty = threadIdx.x >> 5;  // ty in 0..7
#pragma unroll
  for (int i = 0; i < 32; i += 8)
    tile[ty + i][tx] = in[(long)(r0 + ty + i) * C + c0 + tx];
  __syncthreads();
#pragma unroll
  for (int i = 0; i < 32; i += 8)
    out[(long)(c0 + ty + i) * ostride + r0 + tx] = f2bf(tile[tx][ty + i]);
}

// ---- concat biases bq|bk|bv -> [5120] fp32 ----
__global__ __launch_bounds__(256) void concat_bias(const float* bq, const float* bk,
                                                   const float* bv, float* out) {
  int t = blockIdx.x * 256 + threadIdx.x;
  if (t < 4096) out[t] = bq[t];
  else if (t < 4608) out[t] = bk[t - 4096];
  else if (t < 5120) out[t] = bv[t - 4608];
}

// ---- pipelined GEMM: C[M][N] = A[M][K] @ B_t[N][K]^T + bias ----
// 128x128 tile, BK=32, 3 LDS buffers, counted-vmcnt prefetch depth 2,
// T2 LDS XOR swizzle (source-side), T5 setprio, T1 XCD-aware block swizzle.
template <bool OUT_BF16>
__global__ __launch_bounds__(256, 3) void gemm_pipe(const u16* __restrict__ A,
                                                    const u16* __restrict__ B,
                                                    const float* __restrict__ bias,
                                                    void* __restrict__ Cout,
                                                    int M, int N, int K) {
  __shared__ u16 As[3][128 * 32];
  __shared__ u16 Bs[3][128 * 32];
  const int tid = threadIdx.x;
  const int wid = tid >> 6, lane = tid & 63;
  const int lr = lane & 15, lk = lane >> 4;
  const int wm = wid >> 1, wn = wid & 1;

  // T1: bijective XCD swizzle (m204 form)
  const int gm = gridDim.x;
  int nwg = gm * gridDim.y;
  int bid = blockIdx.y * gm + blockIdx.x;
  int q8 = nwg >> 3, r8 = nwg & 7;
  int xcd = bid & 7, seq = bid >> 3;
  int swz = (xcd < r8 ? xcd * (q8 + 1) : r8 * (q8 + 1) + (xcd - r8) * q8) + seq;
  const long brow = (long)(swz % gm) * 128;
  const long bcol = (long)(swz / gm) * 128;

  // staging constants (2 chunks of A + 2 of B per thread per tile = 4 loads)
  const int c0 = wid * 128 + lane;      // 0..511 (i=0)
  const int c1 = c0 + 64;               // (i=1)
  const int r0s = c0 >> 2, k0s = ((c0 & 3) ^ ((r0s >> 1) & 3)) * 8;
  const int r1s = c1 >> 2, k1s = ((c1 & 3) ^ ((r1s >> 1) & 3)) * 8;
  const u16* Asrc0 = A + (brow + r0s) * (long)K + k0s;
  const u16* Asrc1 = A + (brow + r1s) * (long)K + k1s;
  const u16* Bsrc0 = B + (bcol + r0s) * (long)K + k0s;
  const u16* Bsrc1 = B + (bcol + r1s) * (long)K + k1s;
  char* AsB = (char*)&As[0][0];
  char* BsB = (char*)&Bs[0][0];

  auto stage = [&](int kt, int bufi) {
    long ko = (long)kt * 32;
    char* la = AsB + bufi * 8192;
    char* lb = BsB + bufi * 8192;
    async_load16(Asrc0 + ko, la + c0 * 16);
    async_load16(Bsrc0 + ko, lb + c0 * 16);
    async_load16(Asrc1 + ko, la + c1 * 16);
    async_load16(Bsrc1 + ko, lb + c1 * 16);
  };

  // fragment read offsets: phys slot = lk ^ ((lr>>1)&3)  (2-way, free)
  const int phys = (lk ^ ((lr >> 1) & 3)) << 4;
  const int aoff0 = (wm * 64 + lr) * 64 + phys;  // bytes; + m*1024
  const int boff0 = (wn * 64 + lr) * 64 + phys;  // bytes; + n*1024

  f32x4 acc[4][4] = {};
  const int nk = K >> 5;

  stage(0, 0);
  if (nk > 1) stage(1, 1);

  int b = 0, sb = 2;
  for (int kt = 0; kt < nk; ++kt) {
    if (kt + 1 < nk) { ASM_VMCNT4(); } else { ASM_VMCNT0(); }
    ASM_BARRIER();
    __builtin_amdgcn_sched_barrier(0);
    if (kt + 2 < nk) stage(kt + 2, sb);
    char* Ab_ = AsB + b * 8192;
    char* Bb_ = BsB + b * 8192;
    bf16x8 af[4], bfr[4];
#pragma unroll
    for (int m = 0; m < 4; ++m) af[m] = *(const bf16x8*)(Ab_ + aoff0 + m * 1024);
#pragma unroll
    for (int n = 0; n < 4; ++n) bfr[n] = *(const bf16x8*)(Bb_ + boff0 + n * 1024);
    ASM_LGKM0();
    __builtin_amdgcn_sched_barrier(0);
    __builtin_amdgcn_s_setprio(1);
#pragma unroll
    for (int m = 0; m < 4; ++m)
#pragma unroll
      for (int n = 0; n < 4; ++n)
        acc[m][n] = __builtin_amdgcn_mfma_f32_16x16x32_bf16(af[m], bfr[n], acc[m][n], 0, 0, 0);
    __builtin_amdgcn_s_setprio(0);
    b = (b == 2) ? 0 : b + 1;
    sb = (sb == 2) ? 0 : sb + 1;
  }

  // epilogue
#pragma unroll
  for (int m = 0; m < 4; ++m) {
    long row = brow + wm * 64 + m * 16 + lk * 4;
#pragma unroll
    for (int n = 0; n < 4; ++n) {
      long col = bcol + wn * 64 + n * 16 + lr;
      if (col < N) {
        float bv = bias[col];
#pragma unroll
        for (int r = 0; r < 4; ++r) {
          float v = acc[m][n][r] + bv;
          if (OUT_BF16) ((u16*)Cout)[(row + r) * (long)N + col] = f2bf(v);
          else          ((float*)Cout)[(row + r) * (long)N + col] = v;
        }
      }
    }
  }
}

// ---- RoPE in-place on QKV bf16 buffer (q heads 0..63, k heads 64..71) ----
__global__ __launch_bounds__(256) void rope_kernel(u16* __restrict__ QKV,
                                                   const float* __restrict__ cosb,
                                                   const float* __restrict__ sinb) {
  long idx = (long)blockIdx.x * 256 + threadIdx.x;  // SEQ*72*32
  if (idx >= (long)SEQ * 72 * 32) return;
  int d = idx & 31;
  int h = (int)((idx >> 5) % 72);
  int s = (int)(idx / (72 * 32));
  int col = (h < 64) ? h * 64 : 4096 + (h - 64) * 64;
  u16* p = QKV + (long)s * NQKV + col;
  float x1 = bf2f(p[d]), x2 = bf2f(p[d + 32]);
  float c = cosb[s * 64 + d], sn = sinb[s * 64 + d];
  p[d]      = f2bf(x1 * c - x2 * sn);
  p[d + 32] = f2bf(x2 * c + x1 * sn);
}

// ---- sliding-window attention with sinks ----
// grid: (SEQ/64, NHEAD/4); block 256 (4 waves, 1 head each, shared KV group)
// K and V LDS tiles are XOR-swizzled (16-way -> 2-way bank conflicts).
__global__ __launch_bounds__(256, 1) void attn_kernel(const u16* __restrict__ QKV,
                                                      const float* __restrict__ sinks,
                                                      u16* __restrict__ Oa) {
  __shared__ u16 Ks[64 * 64];
  __shared__ u16 Vt[64 * 64];        // logical [d][j], swizzled
  __shared__ u16 Ps[4][64 * 72];     // per-wave P, padded stride 72
  const int tid = threadIdx.x, wid = tid >> 6, lane = tid & 63;
  const int lr = lane & 15, lk = lane >> 4;
  const int i0 = blockIdx.x * 64;
  const int h = blockIdx.y * 4 + wid;
  const int g = h >> 3;

  // Q fragments (post-RoPE, bf16)
  bf16x8 qf[4][2];
#pragma unroll
  for (int m = 0; m < 4; ++m)
#pragma unroll
    for (int kc = 0; kc < 2; ++kc)
      qf[m][kc] = *(const bf16x8*)&QKV[(long)(i0 + m * 16 + lr) * NQKV + h * 64 + kc * 32 + lk * 8];

  const float sinkh = sinks[h];
  float mrun[4][4], lrun[4][4];
  f32x4 oacc[4][4] = {};
#pragma unroll
  for (int m = 0; m < 4; ++m)
#pragma unroll
    for (int r = 0; r < 4; ++r) { mrun[m][r] = sinkh; lrun[m][r] = 0.f; }

  const int jb0 = (i0 >= 128) ? (i0 - 128) : 0;
  for (int jb = jb0; jb <= i0; jb += 64) {
    // K block -> LDS (async, source pre-swizzled: slot ^= row&7)
#pragma unroll
    for (int i = 0; i < 2; ++i) {
      int c = wid * 128 + i * 64 + lane;  // 0..511
      int row = c >> 3, sp = c & 7;
      int ssrc = sp ^ (row & 7);
      async_load16(QKV + (long)(jb + row) * NQKV + 4096 + g * 64 + ssrc * 8,
                   ((char*)Ks) + c * 16);
    }
    // V block -> LDS transposed [d][j], swizzled, packed b32 writes
    {
      int j0 = (tid & 31) * 2, d0 = (tid >> 5) * 8;
      const u16* vp = QKV + (long)(jb + j0) * NQKV + 4608 + g * 64 + d0;
      int4 rv0 = *(const int4*)vp;
      int4 rv1 = *(const int4*)(vp + NQKV);
      const u16* a0 = (const u16*)&rv0;
      const u16* a1 = (const u16*)&rv1;
#pragma unroll
      for (int e = 0; e < 8; ++e) {
        int d = d0 + e;
        unsigned val = (unsigned)a0[e] | ((unsigned)a1[e] << 16);
        int byt = d * 128 + ((((j0 >> 3) ^ (d & 7)) << 4)) + ((j0 & 7) * 2);
        *(unsigned*)((char*)Vt + byt) = val;
      }
    }
    __syncthreads();

    // S = Q K^T
    f32x4 sf[4][4] = {};
    __builtin_amdgcn_s_setprio(1);
#pragma unroll
    for (int kc = 0; kc < 2; ++kc) {
      bf16x8 kf[4];
#pragma unroll
      for (int cf = 0; cf < 4; ++cf) {
        int row = cf * 16 + lr;
        kf[cf] = *(const bf16x8*)((const char*)Ks + row * 128 + (((kc * 4 + lk) ^ (lr & 7)) << 4));
      }
#pragma unroll
      for (int m = 0; m < 4; ++m)
#pragma unroll
        for (int cf = 0; cf < 4; ++cf)
          sf[m][cf] = __builtin_amdgcn_mfma_f32_16x16x32_bf16(qf[m][kc], kf[cf], sf[m][cf], 0, 0, 0);
    }
    __builtin_amdgcn_s_setprio(0);

    // scale + mask + online softmax
#pragma unroll
    for (int m = 0; m < 4; ++m) {
      float rmax[4];
#pragma unroll
      for (int r = 0; r < 4; ++r) {
        int i = i0 + m * 16 + lk * 4 + r;
        float mx = NEG_INF;
#pragma unroll
        for (int cf = 0; cf < 4; ++cf) {
          int j = jb + cf * 16 + lr;
          float v = sf[m][cf][r] * SCALE;
          bool ok = (j <= i) && (j > i - 128);
          v = ok ? v : NEG_INF;
          sf[m][cf][r] = v;
          mx = fmaxf(mx, v);
        }
#pragma unroll
        for (int off = 1; off < 16; off <<= 1) mx = fmaxf(mx, __shfl_xor(mx, off, 64));
        rmax[r] = mx;
      }
#pragma unroll
      for (int r = 0; r < 4; ++r) {
        float mnew = fmaxf(mrun[m][r], rmax[r]);
        float corr = __expf(mrun[m][r] - mnew);
        mrun[m][r] = mnew;
        float rsum = 0.f;
#pragma unroll
        for (int cf = 0; cf < 4; ++cf) {
          float p = __expf(sf[m][cf][r] - mnew);
          sf[m][cf][r] = p;
          rsum += p;
        }
#pragma unroll
        for (int off = 1; off < 16; off <<= 1) rsum += __shfl_xor(rsum, off, 64);
        lrun[m][r] = lrun[m][r] * corr + rsum;
#pragma unroll
        for (int dn = 0; dn < 4; ++dn) oacc[m][dn][r] *= corr;
      }
    }

    // P -> bf16 -> LDS (C-layout rows)
#pragma unroll
    for (int m = 0; m < 4; ++m)
#pragma unroll
      for (int cf = 0; cf < 4; ++cf)
#pragma unroll
        for (int r = 0; r < 4; ++r)
          Ps[wid][(m * 16 + lk * 4 + r) * 72 + cf * 16 + lr] = f2bf(sf[m][cf][r]);
    __syncthreads();

    // O += P V
    __builtin_amdgcn_s_setprio(1);
#pragma unroll
    for (int kc = 0; kc < 2; ++kc) {
      bf16x8 pf[4], vf[4];
#pragma unroll
      for (int m = 0; m < 4; ++m)
        pf[m] = *(const bf16x8*)&Ps[wid][(m * 16 + lr) * 72 + kc * 32 + lk * 8];
#pragma unroll
      for (int dn = 0; dn < 4; ++dn) {
        int row = dn * 16 + lr;
        vf[dn] = *(const bf16x8*)((const char*)Vt + row * 128 + (((kc * 4 + lk) ^ (lr & 7)) << 4));
      }
#pragma unroll
      for (int m = 0; m < 4; ++m)
#pragma unroll
        for (int dn = 0; dn < 4; ++dn)
          oacc[m][dn] = __builtin_amdgcn_mfma_f32_16x16x32_bf16(pf[m], vf[dn], oacc[m][dn], 0, 0, 0);
    }
    __builtin_amdgcn_s_setprio(0);
    __syncthreads();
  }

  // epilogue: divide by denom (incl. sink) and store bf16
#pragma unroll
  for (int m = 0; m < 4; ++m)
#pragma unroll
    for (int r = 0; r < 4; ++r) {
      float denom = lrun[m][r] + __expf(sinkh - mrun[m][r]);
      float inv = 1.f / denom;
      long row = i0 + m * 16 + lk * 4 + r;
#pragma unroll
      for (int dn = 0; dn < 4; ++dn)
        Oa[row * 4096 + h * 64 + dn * 16 + lr] = f2bf(oacc[m][dn][r] * inv);
    }
}

extern "C" void kernel_launch(void* const* d_in, const int* in_sizes, int n_in,
                              void* d_out, int out_size, void* d_ws, size_t ws_size,
                              hipStream_t stream) {
  const float* X    = (const float*)d_in[0];
  const float* cosb = (const float*)d_in[1];
  const float* sinb = (const float*)d_in[2];
  const float* Wq   = (const float*)d_in[3];
  const float* bq   = (const float*)d_in[4];
  const float* Wk   = (const float*)d_in[5];
  const float* bk   = (const float*)d_in[6];
  const float* Wv   = (const float*)d_in[7];
  const float* bv   = (const float*)d_in[8];
  const float* Wo   = (const float*)d_in[9];
  const float* bo   = (const float*)d_in[10];
  const float* sinks = (const float*)d_in[11];

  char* ws = (char*)d_ws;
  size_t off = 0;
  auto alloc = [&](size_t bytes) -> void* {
    void* p = ws + off;
    off += (bytes + 255) & ~(size_t)255;
    return p;
  };
  u16*   Xb    = (u16*)alloc((size_t)SEQ * HIDN * 2);            // [2048][2880]
  u16*   Wqkv  = (u16*)alloc((size_t)NQKV * HIDN * 2);           // [5120][2880]
  u16*   Wot   = (u16*)alloc((size_t)2944 * 4096 * 2);           // [2944][4096] (pad rows)
  float* bqkv  = (float*)alloc((size_t)NQKV * 4);
  u16*   QKV   = (u16*)alloc((size_t)SEQ * NQKV * 2);            // [2048][5120]
  u16*   Ab    = (u16*)alloc((size_t)SEQ * 4096 * 2);            // attn out [2048][4096]
  (void)ws_size; (void)in_sizes; (void)n_in; (void)out_size;

  // 1) convert hidden to bf16
  conv_f2b<<<(SEQ * HIDN / 4 + 255) / 256, 256, 0, stream>>>(X, Xb, (long)SEQ * HIDN / 4);
  // 2) transpose-convert weights into B^T bf16 layouts
  transpose_f2b<<<dim3(4096 / 32, HIDN / 32), 256, 0, stream>>>(Wq, Wqkv, HIDN, 4096, HIDN);
  transpose_f2b<<<dim3(512 / 32, HIDN / 32), 256, 0, stream>>>(Wk, Wqkv + (size_t)4096 * HIDN, HIDN, 512, HIDN);
  transpose_f2b<<<dim3(512 / 32, HIDN / 32), 256, 0, stream>>>(Wv, Wqkv + (size_t)4608 * HIDN, HIDN, 512, HIDN);
  transpose_f2b<<<dim3(HIDN / 32, 4096 / 32), 256, 0, stream>>>(Wo, Wot, 4096, HIDN, 4096);
  concat_bias<<<(NQKV + 255) / 256, 256, 0, stream>>>(bq, bk, bv, bqkv);
  // 3) QKV projection (bf16 out)
  gemm_pipe<true><<<dim3(SEQ / 128, NQKV / 128), 256, 0, stream>>>(Xb, Wqkv, bqkv, QKV, SEQ, NQKV, HIDN);
  // 4) RoPE on q,k
  rope_kernel<<<(int)(((long)SEQ * 72 * 32 + 255) / 256), 256, 0, stream>>>(QKV, cosb, sinb);
  // 5) sliding-window attention with sinks
  attn_kernel<<<dim3(SEQ / 64, 64 / 4), 256, 0, stream>>>(QKV, sinks, Ab);
  // 6) output projection (fp32 out + bo)
  gemm_pipe<false><<<dim3(SEQ / 128, (HIDN + 127) / 128), 256, 0, stream>>>(Ab, Wot, bo, d_out, SEQ, HIDN, 4096);
}

// Round 3
// 248.819 us; speedup vs baseline: 1.0749x; 1.0437x over previous
//
#include <hip/hip_runtime.h>

typedef unsigned short u16;
typedef __bf16 bf16x8 __attribute__((ext_vector_type(8)));
typedef float f32x4 __attribute__((ext_vector_type(4)));

// ---- problem constants ----
constexpr int SEQ = 2048;
constexpr int HIDN = 2880;
constexpr int NQKV = 5120;   // 4096 q | 512 k | 512 v
constexpr float SCALE = 0.125f;   // 1/sqrt(64)
constexpr float NEG_INF = -1e30f;

#define ASM_VMCNT(n)  asm volatile("s_waitcnt vmcnt(" #n ")" ::: "memory")
#define ASM_LGKM0()   asm volatile("s_waitcnt lgkmcnt(0)" ::: "memory")
#define ASM_BARRIER() asm volatile("s_barrier" ::: "memory")
#define SCHEDBAR()    __builtin_amdgcn_sched_barrier(0)

__device__ __forceinline__ u16 f2bf(float f) {
  unsigned int u = __builtin_bit_cast(unsigned int, f);
  u += 0x7FFFu + ((u >> 16) & 1u);
  return (u16)(u >> 16);
}
__device__ __forceinline__ float bf2f(u16 h) {
  unsigned int u = ((unsigned int)h) << 16;
  return __builtin_bit_cast(float, u);
}
__device__ __forceinline__ void async_load16(const void* g, void* l) {
  __builtin_amdgcn_global_load_lds(
      (const __attribute__((address_space(1))) unsigned int*)g,
      (__attribute__((address_space(3))) unsigned int*)l, 16, 0, 0);
}
// asm ds_read_b128: opaque to compiler mem-dep tracking (prevents auto vmcnt
// drains against global_load_lds); ordering enforced by volatile-asm fences.
__device__ __forceinline__ f32x4 DSR(unsigned addr) {
  f32x4 d;
  asm volatile("ds_read_b128 %0, %1" : "=v"(d) : "v"(addr));
  return d;
}
__device__ __forceinline__ bf16x8 asbf(f32x4 v) { return __builtin_bit_cast(bf16x8, v); }

// ---- fp32 -> bf16 flat convert ----
__global__ __launch_bounds__(256) void conv_f2b(const float* __restrict__ in,
                                                u16* __restrict__ out, long n4) {
  long i = (long)blockIdx.x * 256 + threadIdx.x;
  if (i >= n4) return;
  float4 v = ((const float4*)in)[i];
  u16 o0 = f2bf(v.x), o1 = f2bf(v.y), o2 = f2bf(v.z), o3 = f2bf(v.w);
  out[i * 4 + 0] = o0; out[i * 4 + 1] = o1; out[i * 4 + 2] = o2; out[i * 4 + 3] = o3;
}

// ---- fp32 [R][C] -> bf16 out[c][r] (transpose-convert), dims % 32 == 0 ----
__global__ __launch_bounds__(256) void transpose_f2b(const float* __restrict__ in,
                                                     u16* __restrict__ out,
                                                     int R, int C, int ostride) {
  __shared__ float tile[32][33];
  int c0 = blockIdx.x * 32, r0 = blockIdx.y * 32;
  int tx = threadIdx.x & 31, ty = threadIdx.x >> 5;
#pragma unroll
  for (int i = 0; i < 32; i += 8)
    tile[ty + i][tx] = in[(long)(r0 + ty + i) * C + c0 + tx];
  __syncthreads();
#pragma unroll
  for (int i = 0; i < 32; i += 8)
    out[(long)(c0 + ty + i) * ostride + r0 + tx] = f2bf(tile[tx][ty + i]);
}

__global__ __launch_bounds__(256) void concat_bias(const float* bq, const float* bk,
                                                   const float* bv, float* out) {
  int t = blockIdx.x * 256 + threadIdx.x;
  if (t < 4096) out[t] = bq[t];
  else if (t < 4608) out[t] = bk[t - 4096];
  else if (t < 5120) out[t] = bv[t - 4608];
}

// ============ GEMM A: BM=256,BN=256,BK=32, 512thr (2Mx4N waves) =============
// Triple-buffered 32KB K-tiles; 2 phases/K-tile; stage(t+2)@P1; vmcnt(4)@P2.
__global__ __launch_bounds__(512, 2) void gemm256(const u16* __restrict__ A,
                                                  const u16* __restrict__ B,
                                                  const float* __restrict__ bias,
                                                  u16* __restrict__ C,
                                                  int N, int K) {
  __shared__ u16 lds[3 * 16384];  // per buf: A[256][32] | B[256][32] = 32KB
  const int tid = threadIdx.x, wid = tid >> 6, lane = tid & 63;
  const int lr = lane & 15, lk = lane >> 4;
  const int wm = wid >> 2, wn = wid & 3;

  const int gm = gridDim.x;
  int nwg = gm * gridDim.y;
  int bid = blockIdx.y * gm + blockIdx.x;
  int q8 = nwg >> 3, r8 = nwg & 7;
  int xcd = bid & 7, seq = bid >> 3;
  int swz = (xcd < r8 ? xcd * (q8 + 1) : r8 * (q8 + 1) + (xcd - r8) * q8) + seq;
  const long brow = (long)(swz % gm) * 256;
  const long bcol = (long)(swz / gm) * 256;
  const int nkt = K >> 5;

  const int cA0 = tid, cA1 = tid + 512;            // 16B chunks, rows of 64B
  const u16* Asrc0 = A + (brow + (cA0 >> 2)) * (long)K + (cA0 & 3) * 8;
  const u16* Asrc1 = A + (brow + (cA1 >> 2)) * (long)K + (cA1 & 3) * 8;
  const u16* Bsrc0 = B + (bcol + (cA0 >> 2)) * (long)K + (cA0 & 3) * 8;
  const u16* Bsrc1 = B + (bcol + (cA1 >> 2)) * (long)K + (cA1 & 3) * 8;
  char* L = (char*)lds;
  auto stage = [&](int kt, int b) {
    long ko = (long)kt * 32;
    char* d = L + b * 32768;
    async_load16(Asrc0 + ko, d + cA0 * 16);
    async_load16(Asrc1 + ko, d + cA1 * 16);
    async_load16(Bsrc0 + ko, d + 16384 + cA0 * 16);
    async_load16(Bsrc1 + ko, d + 16384 + cA1 * 16);
  };

  const unsigned lds0 = (unsigned)(size_t)L;
  const unsigned aoff = lds0 + (unsigned)((wm * 128 + lr) * 64 + lk * 16);
  const unsigned boff = lds0 + 16384u + (unsigned)((wn * 64 + lr) * 64 + lk * 16);

  f32x4 acc[8][4] = {};
  stage(0, 0);
  stage(1, 1);
  ASM_VMCNT(4);
  ASM_BARRIER();

  int b = 0;
  for (int t = 0; t < nkt; ++t) {
    const unsigned ab = aoff + b * 32768u;
    const unsigned bb = boff + b * 32768u;
    // ---- P1: reads (A m0-3, B n0-3) + stage(t+2) + MFMA quad 1 ----
    f32x4 afr[4], bfr[4];
#pragma unroll
    for (int m = 0; m < 4; ++m) afr[m] = DSR(ab + m * 1024u);
#pragma unroll
    for (int n = 0; n < 4; ++n) bfr[n] = DSR(bb + n * 1024u);
    if (t + 2 < nkt) stage(t + 2, b == 0 ? 2 : b - 1);  // (t+2)%3
    ASM_LGKM0(); SCHEDBAR();
    __builtin_amdgcn_s_setprio(1);
#pragma unroll
    for (int m = 0; m < 4; ++m)
#pragma unroll
      for (int n = 0; n < 4; ++n)
        acc[m][n] = __builtin_amdgcn_mfma_f32_16x16x32_bf16(asbf(afr[m]), asbf(bfr[n]), acc[m][n], 0, 0, 0);
    __builtin_amdgcn_s_setprio(0);
    // ---- P2: reads (A m4-7) + counted vmcnt + barrier + MFMA quad 2 ----
    f32x4 afr2[4];
#pragma unroll
    for (int m = 0; m < 4; ++m) afr2[m] = DSR(ab + (m + 4) * 1024u);
    if (t + 2 < nkt) { ASM_VMCNT(4); } else { ASM_VMCNT(0); }
    ASM_BARRIER();
    ASM_LGKM0(); SCHEDBAR();
    __builtin_amdgcn_s_setprio(1);
#pragma unroll
    for (int m = 0; m < 4; ++m)
#pragma unroll
      for (int n = 0; n < 4; ++n)
        acc[m + 4][n] = __builtin_amdgcn_mfma_f32_16x16x32_bf16(asbf(afr2[m]), asbf(bfr[n]), acc[m + 4][n], 0, 0, 0);
    __builtin_amdgcn_s_setprio(0);
    ASM_BARRIER();
    b = (b == 2) ? 0 : b + 1;
  }

#pragma unroll
  for (int m = 0; m < 8; ++m) {
    long row = brow + wm * 128 + m * 16 + lk * 4;
#pragma unroll
    for (int n = 0; n < 4; ++n) {
      long col = bcol + wn * 64 + n * 16 + lr;
      float bv = bias[col];
#pragma unroll
      for (int r = 0; r < 4; ++r)
        C[(row + r) * (long)N + col] = f2bf(acc[m][n][r] + bv);
    }
  }
}

// ============ GEMM B: BM=128,BN=256,BK=32, 512thr (2Mx4N waves) =============
// Quad-buffered 24KB K-tiles; 1 phase/K-tile; stage(t+3); vmcnt(6).
__global__ __launch_bounds__(512, 2) void gemm128(const u16* __restrict__ A,
                                                  const u16* __restrict__ B,
                                                  const float* __restrict__ bias,
                                                  float* __restrict__ C,
                                                  int N, int K) {
  __shared__ u16 lds[4 * 12288];  // per buf: A[128][32] (8KB) | B[256][32] (16KB)
  const int tid = threadIdx.x, wid = tid >> 6, lane = tid & 63;
  const int lr = lane & 15, lk = lane >> 4;
  const int wm = wid >> 2, wn = wid & 3;

  const int gm = gridDim.x;
  int nwg = gm * gridDim.y;
  int bid = blockIdx.y * gm + blockIdx.x;
  int q8 = nwg >> 3, r8 = nwg & 7;
  int xcd = bid & 7, seq = bid >> 3;
  int swz = (xcd < r8 ? xcd * (q8 + 1) : r8 * (q8 + 1) + (xcd - r8) * q8) + seq;
  const long brow = (long)(swz % gm) * 128;
  const long bcol = (long)(swz / gm) * 256;
  const int nkt = K >> 5;

  const int cB0 = tid, cB1 = tid + 512;
  const u16* AsrcP = A + (brow + (tid >> 2)) * (long)K + (tid & 3) * 8;  // 512 chunks
  const u16* Bsrc0 = B + (bcol + (cB0 >> 2)) * (long)K + (cB0 & 3) * 8;
  const u16* Bsrc1 = B + (bcol + (cB1 >> 2)) * (long)K + (cB1 & 3) * 8;
  char* L = (char*)lds;
  auto stage = [&](int kt, int b) {
    long ko = (long)kt * 32;
    char* d = L + b * 24576;
    async_load16(AsrcP + ko, d + tid * 16);
    async_load16(Bsrc0 + ko, d + 8192 + cB0 * 16);
    async_load16(Bsrc1 + ko, d + 8192 + cB1 * 16);
  };

  const unsigned lds0 = (unsigned)(size_t)L;
  const unsigned aoff = lds0 + (unsigned)((wm * 64 + lr) * 64 + lk * 16);
  const unsigned boff = lds0 + 8192u + (unsigned)((wn * 64 + lr) * 64 + lk * 16);

  f32x4 acc[4][4] = {};
  stage(0, 0);
  stage(1, 1);
  stage(2, 2);
  ASM_VMCNT(6);
  ASM_BARRIER();

  for (int t = 0; t < nkt; ++t) {
    const int b = t & 3;
    const unsigned ab = aoff + b * 24576u;
    const unsigned bb = boff + b * 24576u;
    f32x4 afr[4], bfr[4];
#pragma unroll
    for (int m = 0; m < 4; ++m) afr[m] = DSR(ab + m * 1024u);
#pragma unroll
    for (int n = 0; n < 4; ++n) bfr[n] = DSR(bb + n * 1024u);
    if (t + 3 < nkt) stage(t + 3, (t + 3) & 3);
    if (t + 3 < nkt)      { ASM_VMCNT(6); }
    else if (t + 2 < nkt) { ASM_VMCNT(3); }
    else                  { ASM_VMCNT(0); }
    ASM_BARRIER();
    ASM_LGKM0(); SCHEDBAR();
    __builtin_amdgcn_s_setprio(1);
#pragma unroll
    for (int m = 0; m < 4; ++m)
#pragma unroll
      for (int n = 0; n < 4; ++n)
        acc[m][n] = __builtin_amdgcn_mfma_f32_16x16x32_bf16(asbf(afr[m]), asbf(bfr[n]), acc[m][n], 0, 0, 0);
    __builtin_amdgcn_s_setprio(0);
    ASM_BARRIER();
  }

#pragma unroll
  for (int m = 0; m < 4; ++m) {
    long row = brow + wm * 64 + m * 16 + lk * 4;
#pragma unroll
    for (int n = 0; n < 4; ++n) {
      long col = bcol + wn * 64 + n * 16 + lr;
      if (col < N) {
        float bv = bias[col];
#pragma unroll
        for (int r = 0; r < 4; ++r)
          C[(row + r) * (long)N + col] = acc[m][n][r] + bv;
      }
    }
  }
}

// ---- RoPE in-place on QKV bf16 buffer (q heads 0..63, k heads 64..71) ----
__global__ __launch_bounds__(256) void rope_kernel(u16* __restrict__ QKV,
                                                   const float* __restrict__ cosb,
                                                   const float* __restrict__ sinb) {
  long idx = (long)blockIdx.x * 256 + threadIdx.x;
  if (idx >= (long)SEQ * 72 * 32) return;
  int d = idx & 31;
  int h = (int)((idx >> 5) % 72);
  int s = (int)(idx / (72 * 32));
  int col = (h < 64) ? h * 64 : 4096 + (h - 64) * 64;
  u16* p = QKV + (long)s * NQKV + col;
  float x1 = bf2f(p[d]), x2 = bf2f(p[d + 32]);
  float c = cosb[s * 64 + d], sn = sinb[s * 64 + d];
  p[d]      = f2bf(x1 * c - x2 * sn);
  p[d + 32] = f2bf(x2 * c + x1 * sn);
}

// ---- sliding-window attention with sinks (unchanged from R2) ----
__global__ __launch_bounds__(256, 1) void attn_kernel(const u16* __restrict__ QKV,
                                                      const float* __restrict__ sinks,
                                                      u16* __restrict__ Oa) {
  __shared__ u16 Ks[64 * 64];
  __shared__ u16 Vt[64 * 64];
  __shared__ u16 Ps[4][64 * 72];
  const int tid = threadIdx.x, wid = tid >> 6, lane = tid & 63;
  const int lr = lane & 15, lk = lane >> 4;
  const int i0 = blockIdx.x * 64;
  const int h = blockIdx.y * 4 + wid;
  const int g = h >> 3;

  bf16x8 qf[4][2];
#pragma unroll
  for (int m = 0; m < 4; ++m)
#pragma unroll
    for (int kc = 0; kc < 2; ++kc)
      qf[m][kc] = *(const bf16x8*)&QKV[(long)(i0 + m * 16 + lr) * NQKV + h * 64 + kc * 32 + lk * 8];

  const float sinkh = sinks[h];
  float mrun[4][4], lrun[4][4];
  f32x4 oacc[4][4] = {};
#pragma unroll
  for (int m = 0; m < 4; ++m)
#pragma unroll
    for (int r = 0; r < 4; ++r) { mrun[m][r] = sinkh; lrun[m][r] = 0.f; }

  const int jb0 = (i0 >= 128) ? (i0 - 128) : 0;
  for (int jb = jb0; jb <= i0; jb += 64) {
#pragma unroll
    for (int i = 0; i < 2; ++i) {
      int c = wid * 128 + i * 64 + lane;
      int row = c >> 3, sp = c & 7;
      int ssrc = sp ^ (row & 7);
      async_load16(QKV + (long)(jb + row) * NQKV + 4096 + g * 64 + ssrc * 8,
                   ((char*)Ks) + c * 16);
    }
    {
      int j0 = (tid & 31) * 2, d0 = (tid >> 5) * 8;
      const u16* vp = QKV + (long)(jb + j0) * NQKV + 4608 + g * 64 + d0;
      int4 rv0 = *(const int4*)vp;
      int4 rv1 = *(const int4*)(vp + NQKV);
      const u16* a0 = (const u16*)&rv0;
      const u16* a1 = (const u16*)&rv1;
#pragma unroll
      for (int e = 0; e < 8; ++e) {
        int d = d0 + e;
        unsigned val = (unsigned)a0[e] | ((unsigned)a1[e] << 16);
        int byt = d * 128 + ((((j0 >> 3) ^ (d & 7)) << 4)) + ((j0 & 7) * 2);
        *(unsigned*)((char*)Vt + byt) = val;
      }
    }
    __syncthreads();

    f32x4 sf[4][4] = {};
    __builtin_amdgcn_s_setprio(1);
#pragma unroll
    for (int kc = 0; kc < 2; ++kc) {
      bf16x8 kf[4];
#pragma unroll
      for (int cf = 0; cf < 4; ++cf) {
        int row = cf * 16 + lr;
        kf[cf] = *(const bf16x8*)((const char*)Ks + row * 128 + (((kc * 4 + lk) ^ (lr & 7)) << 4));
      }
#pragma unroll
      for (int m = 0; m < 4; ++m)
#pragma unroll
        for (int cf = 0; cf < 4; ++cf)
          sf[m][cf] = __builtin_amdgcn_mfma_f32_16x16x32_bf16(qf[m][kc], kf[cf], sf[m][cf], 0, 0, 0);
    }
    __builtin_amdgcn_s_setprio(0);

#pragma unroll
    for (int m = 0; m < 4; ++m) {
      float rmax[4];
#pragma unroll
      for (int r = 0; r < 4; ++r) {
        int i = i0 + m * 16 + lk * 4 + r;
        float mx = NEG_INF;
#pragma unroll
        for (int cf = 0; cf < 4; ++cf) {
          int j = jb + cf * 16 + lr;
          float v = sf[m][cf][r] * SCALE;
          bool ok = (j <= i) && (j > i - 128);
          v = ok ? v : NEG_INF;
          sf[m][cf][r] = v;
          mx = fmaxf(mx, v);
        }
#pragma unroll
        for (int off = 1; off < 16; off <<= 1) mx = fmaxf(mx, __shfl_xor(mx, off, 64));
        rmax[r] = mx;
      }
#pragma unroll
      for (int r = 0; r < 4; ++r) {
        float mnew = fmaxf(mrun[m][r], rmax[r]);
        float corr = __expf(mrun[m][r] - mnew);
        mrun[m][r] = mnew;
        float rsum = 0.f;
#pragma unroll
        for (int cf = 0; cf < 4; ++cf) {
          float p = __expf(sf[m][cf][r] - mnew);
          sf[m][cf][r] = p;
          rsum += p;
        }
#pragma unroll
        for (int off = 1; off < 16; off <<= 1) rsum += __shfl_xor(rsum, off, 64);
        lrun[m][r] = lrun[m][r] * corr + rsum;
#pragma unroll
        for (int dn = 0; dn < 4; ++dn) oacc[m][dn][r] *= corr;
      }
    }

#pragma unroll
    for (int m = 0; m < 4; ++m)
#pragma unroll
      for (int cf = 0; cf < 4; ++cf)
#pragma unroll
        for (int r = 0; r < 4; ++r)
          Ps[wid][(m * 16 + lk * 4 + r) * 72 + cf * 16 + lr] = f2bf(sf[m][cf][r]);
    __syncthreads();

    __builtin_amdgcn_s_setprio(1);
#pragma unroll
    for (int kc = 0; kc < 2; ++kc) {
      bf16x8 pf[4], vf[4];
#pragma unroll
      for (int m = 0; m < 4; ++m)
        pf[m] = *(const bf16x8*)&Ps[wid][(m * 16 + lr) * 72 + kc * 32 + lk * 8];
#pragma unroll
      for (int dn = 0; dn < 4; ++dn) {
        int row = dn * 16 + lr;
        vf[dn] = *(const bf16x8*)((const char*)Vt + row * 128 + (((kc * 4 + lk) ^ (lr & 7)) << 4));
      }
#pragma unroll
      for (int m = 0; m < 4; ++m)
#pragma unroll
        for (int dn = 0; dn < 4; ++dn)
          oacc[m][dn] = __builtin_amdgcn_mfma_f32_16x16x32_bf16(pf[m], vf[dn], oacc[m][dn], 0, 0, 0);
    }
    __builtin_amdgcn_s_setprio(0);
    __syncthreads();
  }

#pragma unroll
  for (int m = 0; m < 4; ++m)
#pragma unroll
    for (int r = 0; r < 4; ++r) {
      float denom = lrun[m][r] + __expf(sinkh - mrun[m][r]);
      float inv = 1.f / denom;
      long row = i0 + m * 16 + lk * 4 + r;
#pragma unroll
      for (int dn = 0; dn < 4; ++dn)
        Oa[row * 4096 + h * 64 + dn * 16 + lr] = f2bf(oacc[m][dn][r] * inv);
    }
}

extern "C" void kernel_launch(void* const* d_in, const int* in_sizes, int n_in,
                              void* d_out, int out_size, void* d_ws, size_t ws_size,
                              hipStream_t stream) {
  const float* X    = (const float*)d_in[0];
  const float* cosb = (const float*)d_in[1];
  const float* sinb = (const float*)d_in[2];
  const float* Wq   = (const float*)d_in[3];
  const float* bq   = (const float*)d_in[4];
  const float* Wk   = (const float*)d_in[5];
  const float* bk   = (const float*)d_in[6];
  const float* Wv   = (const float*)d_in[7];
  const float* bv   = (const float*)d_in[8];
  const float* Wo   = (const float*)d_in[9];
  const float* bo   = (const float*)d_in[10];
  const float* sinks = (const float*)d_in[11];

  char* ws = (char*)d_ws;
  size_t off = 0;
  auto alloc = [&](size_t bytes) -> void* {
    void* p = ws + off;
    off += (bytes + 255) & ~(size_t)255;
    return p;
  };
  u16*   Xb    = (u16*)alloc((size_t)SEQ * HIDN * 2);            // [2048][2880]
  u16*   Wqkv  = (u16*)alloc((size_t)NQKV * HIDN * 2);           // [5120][2880]
  u16*   Wot   = (u16*)alloc((size_t)3072 * 4096 * 2);           // [3072][4096] (pad rows)
  float* bqkv  = (float*)alloc((size_t)NQKV * 4);
  u16*   QKV   = (u16*)alloc((size_t)SEQ * NQKV * 2);            // [2048][5120]
  u16*   Ab    = (u16*)alloc((size_t)SEQ * 4096 * 2);            // attn out [2048][4096]
  (void)ws_size; (void)in_sizes; (void)n_in; (void)out_size;

  conv_f2b<<<(SEQ * HIDN / 4 + 255) / 256, 256, 0, stream>>>(X, Xb, (long)SEQ * HIDN / 4);
  transpose_f2b<<<dim3(4096 / 32, HIDN / 32), 256, 0, stream>>>(Wq, Wqkv, HIDN, 4096, HIDN);
  transpose_f2b<<<dim3(512 / 32, HIDN / 32), 256, 0, stream>>>(Wk, Wqkv + (size_t)4096 * HIDN, HIDN, 512, HIDN);
  transpose_f2b<<<dim3(512 / 32, HIDN / 32), 256, 0, stream>>>(Wv, Wqkv + (size_t)4608 * HIDN, HIDN, 512, HIDN);
  transpose_f2b<<<dim3(HIDN / 32, 4096 / 32), 256, 0, stream>>>(Wo, Wot, 4096, HIDN, 4096);
  concat_bias<<<(NQKV + 255) / 256, 256, 0, stream>>>(bq, bk, bv, bqkv);
  // QKV projection: [2048][2880] @ [5120][2880]^T -> bf16 [2048][5120]
  gemm256<<<dim3(SEQ / 256, NQKV / 256), 512, 0, stream>>>(Xb, Wqkv, bqkv, QKV, NQKV, HIDN);
  rope_kernel<<<(int)(((long)SEQ * 72 * 32 + 255) / 256), 256, 0, stream>>>(QKV, cosb, sinb);
  attn_kernel<<<dim3(SEQ / 64, 64 / 4), 256, 0, stream>>>(QKV, sinks, Ab);
  // O-proj: [2048][4096] @ [3072pad][4096]^T -> fp32 [2048][2880]
  gemm128<<<dim3(SEQ / 128, 3072 / 256), 512, 0, stream>>>(Ab, Wot, bo, (float*)d_out, HIDN, 4096);
}